// Round 22
// baseline (68.377 us; speedup 1.0000x reference)
//
#include <hip/hip_runtime.h>
#include <hip/hip_fp16.h>

typedef _Float16 f16x8 __attribute__((ext_vector_type(8)));
typedef _Float16 f16x2 __attribute__((ext_vector_type(2)));
typedef float f32x4 __attribute__((ext_vector_type(4)));

namespace {
constexpr int K = 4096;
constexpr int N = 11008;
constexpr int NC = N / 8;            // 1376 packed words per K-row
constexpr int KSPLIT = 16;           // 256-deep K slices (2 quant groups)
constexpr int SLICE_K = K / KSPLIT;  // 256
constexpr int BXW = 32;              // word-cols per block -> 128B/row contiguous
constexpr int BK = 32;               // K rows per MFMA step
constexpr int NT = SLICE_K / BK;     // 8 steps
constexpr int QS = SLICE_K + 4;      // q LDS col stride, words (260)
constexpr int XSH = 272;             // x LDS row stride, halfs
constexpr int OUT_ELEMS = 32 * N;    // 352256
}

// sum 16 f16 K-slice partials + bias -> out (8 outputs per thread)
__global__ void reduce_kernel(const _Float16* __restrict__ partial,
                              const float* __restrict__ bias,
                              float* __restrict__ out) {
  const int idx = (blockIdx.x * 256 + threadIdx.x) * 8;   // 172 blocks exact
  const int n = idx % N;
  const float4 b0 = *reinterpret_cast<const float4*>(bias + n);
  const float4 b1 = *reinterpret_cast<const float4*>(bias + n + 4);
  float a[8] = {b0.x, b0.y, b0.z, b0.w, b1.x, b1.y, b1.z, b1.w};
#pragma unroll
  for (int s = 0; s < KSPLIT; ++s) {
    const f16x8 p = *reinterpret_cast<const f16x8*>(partial + (long)s * OUT_ELEMS + idx);
#pragma unroll
    for (int j = 0; j < 8; ++j) a[j] += (float)p[j];
  }
  float4 o0 = {a[0], a[1], a[2], a[3]}, o1 = {a[4], a[5], a[6], a[7]};
  *reinterpret_cast<float4*>(out + idx)     = o0;
  *reinterpret_cast<float4*>(out + idx + 4) = o1;
}

// MEASUREMENT: sequential-read bandwidth probe over a large ws region.
// Perfectly coalesced f32x4 grid-stride reads; one 4B sink store per thread.
__global__ __launch_bounds__(256) void probe_seq_kernel(
    const float4* __restrict__ src, float* __restrict__ sink, long n4) {
  const long gid = (long)blockIdx.x * 256 + threadIdx.x;
  const long tot = (long)gridDim.x * 256;
  float4 a = {0.f, 0.f, 0.f, 0.f};
  for (long i = gid; i < n4; i += tot) {
    const float4 v = src[i];
    a.x += v.x; a.y += v.y; a.z += v.z; a.w += v.w;
  }
  sink[gid] = a.x + a.y + a.z + a.w;
}

// MEASUREMENT ROUND: gridDim.z = 3 duplicates all work idempotently (same
// values to same partial addresses) to push this kernel above the ~43us
// harness fill kernels so it appears in the rocprof top-5 with counters.
// Body is byte-identical to round 21 (passing, 20.9us).
__global__ __launch_bounds__(512, 4) void awq_gemm_kernel(
    const int* __restrict__ qw, const int* __restrict__ qz,
    const float* __restrict__ sc, const float* __restrict__ x,
    _Float16* __restrict__ partial)
{
  __shared__ int lqs[BXW * QS];         // q tile, col-major [word-col][k]
  __shared__ _Float16 lxh[32 * XSH];    // x tile f16, [row][k]

  const int tid  = threadIdx.x;
  const int lane = tid & 63;
  const int wid  = tid >> 6;      // wave 0..7
  const int kq   = lane >> 4;     // 0..3
  const int c16  = lane & 15;

  const int bx = blockIdx.x, by = blockIdx.y;
  const int n0 = bx * (BXW * 8);  // 256 output cols per block
  const int c0 = bx * BXW;

  // AWQ nibble shift for col (n&7): 4*AWQ_ORDER[n&7], order [0,4,1,5,2,6,3,7]
  const int j7 = c16 & 7;
  const int sh = ((j7 >> 1) | ((j7 & 1) << 2)) << 2;

  int ncol[2], cglob[2], cloc[2];
#pragma unroll
  for (int t2 = 0; t2 < 2; ++t2) {
    ncol[t2]  = n0 + wid * 32 + t2 * 16 + c16;
    cglob[t2] = ncol[t2] >> 3;
    cloc[t2]  = wid * 4 + t2 * 2 + (c16 >> 3);   // local word-col 0..31
  }

  const int kbeg = by * SLICE_K;
  const int g0   = kbeg >> 7;     // first of 2 quant groups in this slice

  // ---- issue ALL global loads up front ----
  const int qr = tid >> 3;        // 0..63
  const int qc = tid & 7;         // 0..7 -> words qc*4..qc*4+3
  int4 qv[4];
#pragma unroll
  for (int rr = 0; rr < 4; ++rr)
    qv[rr] = *reinterpret_cast<const int4*>(
        qw + (long)(kbeg + rr * 64 + qr) * NC + c0 + qc * 4);

  const int xm = tid >> 4;        // 0..31
  const int xo = tid & 15;        // 0..15
  const float* xrow = x + (long)xm * K + kbeg + xo * 16;
  const float4 xa = *reinterpret_cast<const float4*>(xrow);
  const float4 xb = *reinterpret_cast<const float4*>(xrow + 4);
  const float4 xc = *reinterpret_cast<const float4*>(xrow + 8);
  const float4 xd = *reinterpret_cast<const float4*>(xrow + 12);

  // group scalars -> packed f16 constants (while loads are in flight)
  f16x2 s2[2][2], mz2[2][2];      // [group][n-tile]
#pragma unroll
  for (int g = 0; g < 2; ++g)
#pragma unroll
    for (int t2 = 0; t2 < 2; ++t2) {
      const int zq = qz[(g0 + g) * NC + cglob[t2]];
      const _Float16 s16 = (_Float16)sc[(g0 + g) * N + ncol[t2]];
      const _Float16 mz  = (_Float16)(-(float)(1024 + ((zq >> sh) & 15)));
      s2[g][t2][0] = s16; s2[g][t2][1] = s16;
      mz2[g][t2][0] = mz; mz2[g][t2][1] = mz;
    }

  // ---- LDS writes ----
#pragma unroll
  for (int rr = 0; rr < 4; ++rr) {
    const int r = rr * 64 + qr;
    lqs[(qc * 4 + 0) * QS + r] = qv[rr].x;
    lqs[(qc * 4 + 1) * QS + r] = qv[rr].y;
    lqs[(qc * 4 + 2) * QS + r] = qv[rr].z;
    lqs[(qc * 4 + 3) * QS + r] = qv[rr].w;
  }
  {
    union { f16x2 h2[4]; f16x8 h8; } u0, u1;
    u0.h2[0] = __builtin_bit_cast(f16x2, __builtin_amdgcn_cvt_pkrtz(xa.x, xa.y));
    u0.h2[1] = __builtin_bit_cast(f16x2, __builtin_amdgcn_cvt_pkrtz(xa.z, xa.w));
    u0.h2[2] = __builtin_bit_cast(f16x2, __builtin_amdgcn_cvt_pkrtz(xb.x, xb.y));
    u0.h2[3] = __builtin_bit_cast(f16x2, __builtin_amdgcn_cvt_pkrtz(xb.z, xb.w));
    u1.h2[0] = __builtin_bit_cast(f16x2, __builtin_amdgcn_cvt_pkrtz(xc.x, xc.y));
    u1.h2[1] = __builtin_bit_cast(f16x2, __builtin_amdgcn_cvt_pkrtz(xc.z, xc.w));
    u1.h2[2] = __builtin_bit_cast(f16x2, __builtin_amdgcn_cvt_pkrtz(xd.x, xd.y));
    u1.h2[3] = __builtin_bit_cast(f16x2, __builtin_amdgcn_cvt_pkrtz(xd.z, xd.w));
    _Float16* dst = &lxh[xm * XSH + xo * 16];
    *reinterpret_cast<f16x8*>(dst)     = u0.h8;
    *reinterpret_cast<f16x8*>(dst + 8) = u1.h8;
  }

  __syncthreads();               // the ONLY barrier

  f32x4 acc[2][2] = {};          // [m-tile][n-tile]

#pragma unroll
  for (int t = 0; t < NT; ++t) {
    const int g = t >> 2;        // quant group (4 steps/group)
    const f16x8 a0 = *reinterpret_cast<const f16x8*>(&lxh[c16 * XSH + t * BK + kq * 8]);
    const f16x8 a1 = *reinterpret_cast<const f16x8*>(&lxh[(c16 + 16) * XSH + t * BK + kq * 8]);

#pragma unroll
    for (int t2 = 0; t2 < 2; ++t2) {
      const int base = cloc[t2] * QS + t * BK + kq * 8;
      f16x8 b;
#pragma unroll
      for (int half = 0; half < 2; ++half) {
        const int4 q4 = *reinterpret_cast<const int4*>(&lqs[base + 4 * half]);
        const unsigned v0 = __builtin_amdgcn_ubfe((unsigned)q4.x, sh, 4);
        const unsigned v1 = __builtin_amdgcn_ubfe((unsigned)q4.y, sh, 4);
        const unsigned v2 = __builtin_amdgcn_ubfe((unsigned)q4.z, sh, 4);
        const unsigned v3 = __builtin_amdgcn_ubfe((unsigned)q4.w, sh, 4);
        const f16x2 h01 = __builtin_bit_cast(f16x2, (v0 | (v1 << 16)) | 0x64006400u);
        const f16x2 h23 = __builtin_bit_cast(f16x2, (v2 | (v3 << 16)) | 0x64006400u);
        const f16x2 w01 = (h01 + mz2[g][t2]) * s2[g][t2];   // exact (v-z), 1 rnd
        const f16x2 w23 = (h23 + mz2[g][t2]) * s2[g][t2];
        b[4 * half]     = w01[0];
        b[4 * half + 1] = w01[1];
        b[4 * half + 2] = w23[0];
        b[4 * half + 3] = w23[1];
      }
      acc[0][t2] = __builtin_amdgcn_mfma_f32_16x16x32_f16(a0, b, acc[0][t2], 0, 0, 0);
      acc[1][t2] = __builtin_amdgcn_mfma_f32_16x16x32_f16(a1, b, acc[1][t2], 0, 0, 0);
    }
  }

  // ---- epilogue: f16 partials, plain stores (idempotent across z) ----
  _Float16* pp = partial + (long)by * OUT_ELEMS;
#pragma unroll
  for (int mt = 0; mt < 2; ++mt)
#pragma unroll
    for (int t2 = 0; t2 < 2; ++t2)
#pragma unroll
      for (int i = 0; i < 4; ++i) {
        const int row = mt * 16 + kq * 4 + i;
        pp[row * N + ncol[t2]] = (_Float16)acc[mt][t2][i];
      }
}

extern "C" void kernel_launch(void* const* d_in, const int* in_sizes, int n_in,
                              void* d_out, int out_size, void* d_ws, size_t ws_size,
                              hipStream_t stream) {
  const float* x    = (const float*)d_in[0];
  const int* qw     = (const int*)d_in[1];
  const int* qz     = (const int*)d_in[2];
  const float* sc   = (const float*)d_in[3];   // fp16 values delivered as f32
  const float* bias = (const float*)d_in[4];   // fp16 values delivered as f32
  float* out        = (float*)d_out;

  _Float16* partial = (_Float16*)d_ws;         // 16 x 352256 f16 = 11.3 MB

  awq_gemm_kernel<<<dim3(NC / BXW, KSPLIT, 3), 512, 0, stream>>>(qw, qz, sc, x, partial);
  reduce_kernel<<<dim3(OUT_ELEMS / (256 * 8)), 256, 0, stream>>>(partial, bias, out);

  // ---- sequential-read BW probe over ws (after compute; touches only ws) ----
  const size_t src_off  = (size_t)32 << 20;            // ws + 32 MB
  const size_t sink_off = (size_t)16 << 20;            // ws + 16 MB (2 MB sink)
  if (ws_size > src_off + (1 << 20)) {
    const size_t span = ws_size - src_off - (1 << 20); // leave 1 MB tail slack
    const long n4 = (long)(span > ((size_t)232 << 20) ? ((size_t)232 << 20) : span) / 16;
    probe_seq_kernel<<<dim3(2048), 256, 0, stream>>>(
        (const float4*)((char*)d_ws + src_off),
        (float*)((char*)d_ws + sink_off), n4);
  }
}

// Round 23
// 25.680 us; speedup vs baseline: 2.6626x; 2.6626x over previous
//
#include <hip/hip_runtime.h>
#include <hip/hip_fp16.h>

typedef _Float16 f16x8 __attribute__((ext_vector_type(8)));
typedef _Float16 f16x2 __attribute__((ext_vector_type(2)));
typedef float f32x4 __attribute__((ext_vector_type(4)));

namespace {
constexpr int K = 4096;
constexpr int N = 11008;
constexpr int NC = N / 8;            // 1376 packed words per K-row
constexpr int KSPLIT = 16;           // 256-deep K slices (2 quant groups)
constexpr int SLICE_K = K / KSPLIT;  // 256
constexpr int BXW = 32;              // word-cols per block -> 128B/row contiguous
constexpr int BK = 32;               // K rows per MFMA step
constexpr int NT = SLICE_K / BK;     // 8 steps
constexpr int QS = SLICE_K + 4;      // q LDS col stride, words (260)
constexpr int XSH = 272;             // x LDS row stride, halfs
constexpr int OUT_ELEMS = 32 * N;    // 352256
}

// Sequentially stream qweight (22.5 MB) into L3 with the proven-fast
// coalesced pattern; GEMM's strided reads then hit L3 (~4.1 TB/s measured)
// instead of cold HBM (~1.5 TB/s for this stride).
__global__ __launch_bounds__(256) void prefetch_kernel(
    const int4* __restrict__ src, int* __restrict__ sink, int n4) {
  const int gid = blockIdx.x * 256 + threadIdx.x;
  const int tot = gridDim.x * 256;
  int a = 0;
  for (int i = gid; i < n4; i += tot) {
    const int4 v = src[i];
    a += v.x + v.y + v.z + v.w;     // keep loads live
  }
  sink[gid] = a;                    // deterministic per-slot store
}

// sum 16 f16 K-slice partials + bias -> out (8 outputs per thread)
__global__ void reduce_kernel(const _Float16* __restrict__ partial,
                              const float* __restrict__ bias,
                              float* __restrict__ out) {
  const int idx = (blockIdx.x * 256 + threadIdx.x) * 8;   // 172 blocks exact
  const int n = idx % N;
  const float4 b0 = *reinterpret_cast<const float4*>(bias + n);
  const float4 b1 = *reinterpret_cast<const float4*>(bias + n + 4);
  float a[8] = {b0.x, b0.y, b0.z, b0.w, b1.x, b1.y, b1.z, b1.w};
#pragma unroll
  for (int s = 0; s < KSPLIT; ++s) {
    const f16x8 p = *reinterpret_cast<const f16x8*>(partial + (long)s * OUT_ELEMS + idx);
#pragma unroll
    for (int j = 0; j < 8; ++j) a[j] += (float)p[j];
  }
  float4 o0 = {a[0], a[1], a[2], a[3]}, o1 = {a[4], a[5], a[6], a[7]};
  *reinterpret_cast<float4*>(out + idx)     = o0;
  *reinterpret_cast<float4*>(out + idx + 4) = o1;
}

// GEMM body byte-identical to round 21 (passing, 20.9us total).
__global__ __launch_bounds__(512, 4) void awq_gemm_kernel(
    const int* __restrict__ qw, const int* __restrict__ qz,
    const float* __restrict__ sc, const float* __restrict__ x,
    _Float16* __restrict__ partial)
{
  __shared__ int lqs[BXW * QS];         // q tile, col-major [word-col][k]
  __shared__ _Float16 lxh[32 * XSH];    // x tile f16, [row][k]

  const int tid  = threadIdx.x;
  const int lane = tid & 63;
  const int wid  = tid >> 6;      // wave 0..7
  const int kq   = lane >> 4;     // 0..3
  const int c16  = lane & 15;

  const int bx = blockIdx.x, by = blockIdx.y;
  const int n0 = bx * (BXW * 8);  // 256 output cols per block
  const int c0 = bx * BXW;

  // AWQ nibble shift for col (n&7): 4*AWQ_ORDER[n&7], order [0,4,1,5,2,6,3,7]
  const int j7 = c16 & 7;
  const int sh = ((j7 >> 1) | ((j7 & 1) << 2)) << 2;

  int ncol[2], cglob[2], cloc[2];
#pragma unroll
  for (int t2 = 0; t2 < 2; ++t2) {
    ncol[t2]  = n0 + wid * 32 + t2 * 16 + c16;
    cglob[t2] = ncol[t2] >> 3;
    cloc[t2]  = wid * 4 + t2 * 2 + (c16 >> 3);   // local word-col 0..31
  }

  const int kbeg = by * SLICE_K;
  const int g0   = kbeg >> 7;     // first of 2 quant groups in this slice

  // ---- issue ALL global loads up front ----
  const int qr = tid >> 3;        // 0..63
  const int qc = tid & 7;         // 0..7 -> words qc*4..qc*4+3
  int4 qv[4];
#pragma unroll
  for (int rr = 0; rr < 4; ++rr)
    qv[rr] = *reinterpret_cast<const int4*>(
        qw + (long)(kbeg + rr * 64 + qr) * NC + c0 + qc * 4);

  const int xm = tid >> 4;        // 0..31
  const int xo = tid & 15;        // 0..15
  const float* xrow = x + (long)xm * K + kbeg + xo * 16;
  const float4 xa = *reinterpret_cast<const float4*>(xrow);
  const float4 xb = *reinterpret_cast<const float4*>(xrow + 4);
  const float4 xc = *reinterpret_cast<const float4*>(xrow + 8);
  const float4 xd = *reinterpret_cast<const float4*>(xrow + 12);

  // group scalars -> packed f16 constants (while loads are in flight)
  f16x2 s2[2][2], mz2[2][2];      // [group][n-tile]
#pragma unroll
  for (int g = 0; g < 2; ++g)
#pragma unroll
    for (int t2 = 0; t2 < 2; ++t2) {
      const int zq = qz[(g0 + g) * NC + cglob[t2]];
      const _Float16 s16 = (_Float16)sc[(g0 + g) * N + ncol[t2]];
      const _Float16 mz  = (_Float16)(-(float)(1024 + ((zq >> sh) & 15)));
      s2[g][t2][0] = s16; s2[g][t2][1] = s16;
      mz2[g][t2][0] = mz; mz2[g][t2][1] = mz;
    }

  // ---- LDS writes ----
#pragma unroll
  for (int rr = 0; rr < 4; ++rr) {
    const int r = rr * 64 + qr;
    lqs[(qc * 4 + 0) * QS + r] = qv[rr].x;
    lqs[(qc * 4 + 1) * QS + r] = qv[rr].y;
    lqs[(qc * 4 + 2) * QS + r] = qv[rr].z;
    lqs[(qc * 4 + 3) * QS + r] = qv[rr].w;
  }
  {
    union { f16x2 h2[4]; f16x8 h8; } u0, u1;
    u0.h2[0] = __builtin_bit_cast(f16x2, __builtin_amdgcn_cvt_pkrtz(xa.x, xa.y));
    u0.h2[1] = __builtin_bit_cast(f16x2, __builtin_amdgcn_cvt_pkrtz(xa.z, xa.w));
    u0.h2[2] = __builtin_bit_cast(f16x2, __builtin_amdgcn_cvt_pkrtz(xb.x, xb.y));
    u0.h2[3] = __builtin_bit_cast(f16x2, __builtin_amdgcn_cvt_pkrtz(xb.z, xb.w));
    u1.h2[0] = __builtin_bit_cast(f16x2, __builtin_amdgcn_cvt_pkrtz(xc.x, xc.y));
    u1.h2[1] = __builtin_bit_cast(f16x2, __builtin_amdgcn_cvt_pkrtz(xc.z, xc.w));
    u1.h2[2] = __builtin_bit_cast(f16x2, __builtin_amdgcn_cvt_pkrtz(xd.x, xd.y));
    u1.h2[3] = __builtin_bit_cast(f16x2, __builtin_amdgcn_cvt_pkrtz(xd.z, xd.w));
    _Float16* dst = &lxh[xm * XSH + xo * 16];
    *reinterpret_cast<f16x8*>(dst)     = u0.h8;
    *reinterpret_cast<f16x8*>(dst + 8) = u1.h8;
  }

  __syncthreads();               // the ONLY barrier

  f32x4 acc[2][2] = {};          // [m-tile][n-tile]

#pragma unroll
  for (int t = 0; t < NT; ++t) {
    const int g = t >> 2;        // quant group (4 steps/group)
    const f16x8 a0 = *reinterpret_cast<const f16x8*>(&lxh[c16 * XSH + t * BK + kq * 8]);
    const f16x8 a1 = *reinterpret_cast<const f16x8*>(&lxh[(c16 + 16) * XSH + t * BK + kq * 8]);

#pragma unroll
    for (int t2 = 0; t2 < 2; ++t2) {
      const int base = cloc[t2] * QS + t * BK + kq * 8;
      f16x8 b;
#pragma unroll
      for (int half = 0; half < 2; ++half) {
        const int4 q4 = *reinterpret_cast<const int4*>(&lqs[base + 4 * half]);
        const unsigned v0 = __builtin_amdgcn_ubfe((unsigned)q4.x, sh, 4);
        const unsigned v1 = __builtin_amdgcn_ubfe((unsigned)q4.y, sh, 4);
        const unsigned v2 = __builtin_amdgcn_ubfe((unsigned)q4.z, sh, 4);
        const unsigned v3 = __builtin_amdgcn_ubfe((unsigned)q4.w, sh, 4);
        const f16x2 h01 = __builtin_bit_cast(f16x2, (v0 | (v1 << 16)) | 0x64006400u);
        const f16x2 h23 = __builtin_bit_cast(f16x2, (v2 | (v3 << 16)) | 0x64006400u);
        const f16x2 w01 = (h01 + mz2[g][t2]) * s2[g][t2];   // exact (v-z), 1 rnd
        const f16x2 w23 = (h23 + mz2[g][t2]) * s2[g][t2];
        b[4 * half]     = w01[0];
        b[4 * half + 1] = w01[1];
        b[4 * half + 2] = w23[0];
        b[4 * half + 3] = w23[1];
      }
      acc[0][t2] = __builtin_amdgcn_mfma_f32_16x16x32_f16(a0, b, acc[0][t2], 0, 0, 0);
      acc[1][t2] = __builtin_amdgcn_mfma_f32_16x16x32_f16(a1, b, acc[1][t2], 0, 0, 0);
    }
  }

  // ---- epilogue: f16 partials, plain stores ----
  _Float16* pp = partial + (long)by * OUT_ELEMS;
#pragma unroll
  for (int mt = 0; mt < 2; ++mt)
#pragma unroll
    for (int t2 = 0; t2 < 2; ++t2)
#pragma unroll
      for (int i = 0; i < 4; ++i) {
        const int row = mt * 16 + kq * 4 + i;
        pp[row * N + ncol[t2]] = (_Float16)acc[mt][t2][i];
      }
}

extern "C" void kernel_launch(void* const* d_in, const int* in_sizes, int n_in,
                              void* d_out, int out_size, void* d_ws, size_t ws_size,
                              hipStream_t stream) {
  const float* x    = (const float*)d_in[0];
  const int* qw     = (const int*)d_in[1];
  const int* qz     = (const int*)d_in[2];
  const float* sc   = (const float*)d_in[3];   // fp16 values delivered as f32
  const float* bias = (const float*)d_in[4];   // fp16 values delivered as f32
  float* out        = (float*)d_out;

  _Float16* partial = (_Float16*)d_ws;                       // 16 x 352256 f16 = 11.3 MB
  int* sink         = (int*)((char*)d_ws + ((size_t)16 << 20));  // 2 MB sink

  // 1) warm L3 with a sequential sweep of qweight (proven >=5.9 TB/s pattern)
  prefetch_kernel<<<dim3(2048), 256, 0, stream>>>(
      (const int4*)qw, sink, (K * NC) / 4);
  // 2) GEMM (r21 body): strided reads now hit L3 at ~4.1 TB/s
  awq_gemm_kernel<<<dim3(NC / BXW, KSPLIT), 512, 0, stream>>>(qw, qz, sc, x, partial);
  // 3) reduce
  reduce_kernel<<<dim3(OUT_ELEMS / (256 * 8)), 256, 0, stream>>>(partial, bias, out);
}

// Round 24
// 20.775 us; speedup vs baseline: 3.2913x; 1.2361x over previous
//
#include <hip/hip_runtime.h>
#include <hip/hip_fp16.h>

typedef _Float16 f16x8 __attribute__((ext_vector_type(8)));
typedef _Float16 f16x2 __attribute__((ext_vector_type(2)));
typedef float f32x4 __attribute__((ext_vector_type(4)));

namespace {
constexpr int K = 4096;
constexpr int N = 11008;
constexpr int NC = N / 8;            // 1376 packed words per K-row
constexpr int KSPLIT = 16;           // 256-deep K slices (2 quant groups)
constexpr int SLICE_K = K / KSPLIT;  // 256
constexpr int BXW = 32;              // word-cols per block -> 128B/row contiguous
constexpr int BK = 32;               // K rows per MFMA step
constexpr int NT = SLICE_K / BK;     // 8 steps
constexpr int QS = SLICE_K + 4;      // q LDS col stride, words (260)
constexpr int XSH = 272;             // x LDS row stride, halfs
constexpr int OUT_ELEMS = 32 * N;    // 352256
constexpr int NBX = NC / BXW;        // 43 column tiles
constexpr int NWG = NBX * KSPLIT;    // 688 blocks
constexpr int PER_XCD = NWG / 8;     // 86 blocks per XCD
}

// sum 16 f16 K-slice partials + bias -> out (8 outputs per thread)
__global__ void reduce_kernel(const _Float16* __restrict__ partial,
                              const float* __restrict__ bias,
                              float* __restrict__ out) {
  const int idx = (blockIdx.x * 256 + threadIdx.x) * 8;   // 172 blocks exact
  const int n = idx % N;
  const float4 b0 = *reinterpret_cast<const float4*>(bias + n);
  const float4 b1 = *reinterpret_cast<const float4*>(bias + n + 4);
  float a[8] = {b0.x, b0.y, b0.z, b0.w, b1.x, b1.y, b1.z, b1.w};
#pragma unroll
  for (int s = 0; s < KSPLIT; ++s) {
    const f16x8 p = *reinterpret_cast<const f16x8*>(partial + (long)s * OUT_ELEMS + idx);
#pragma unroll
    for (int j = 0; j < 8; ++j) a[j] += (float)p[j];
  }
  float4 o0 = {a[0], a[1], a[2], a[3]}, o1 = {a[4], a[5], a[6], a[7]};
  *reinterpret_cast<float4*>(out + idx)     = o0;
  *reinterpret_cast<float4*>(out + idx + 4) = o1;
}

// r21 body + XCD-aware bijective block swizzle (T1): each XCD owns 2 whole
// k-slices; its 86 blocks collectively stream a CONTIGUOUS 2.8 MB region of
// qweight (adjacent bx = adjacent 128B chunks of the same rows), turning the
// aggregate DRAM pattern into 8 disjoint sequential streams.
__global__ __launch_bounds__(512, 4) void awq_gemm_kernel(
    const int* __restrict__ qw, const int* __restrict__ qz,
    const float* __restrict__ sc, const float* __restrict__ x,
    _Float16* __restrict__ partial)
{
  __shared__ int lqs[BXW * QS];         // q tile, col-major [word-col][k]
  __shared__ _Float16 lxh[32 * XSH];    // x tile f16, [row][k]

  const int tid  = threadIdx.x;
  const int lane = tid & 63;
  const int wid  = tid >> 6;      // wave 0..7
  const int kq   = lane >> 4;     // 0..3
  const int c16  = lane & 15;

  // ---- XCD swizzle: wg -> (by, bx) so XCD k gets by in {2k, 2k+1}, all bx ----
  const int wg  = blockIdx.x;             // 0..687, dispatch round-robins XCDs
  const int wgp = (wg & 7) * PER_XCD + (wg >> 3);   // bijective on [0,688)
  const int by  = wgp / NBX;              // k-slice 0..15
  const int bx  = wgp % NBX;              // column tile 0..42

  const int n0 = bx * (BXW * 8);  // 256 output cols per block
  const int c0 = bx * BXW;

  // AWQ nibble shift for col (n&7): 4*AWQ_ORDER[n&7], order [0,4,1,5,2,6,3,7]
  const int j7 = c16 & 7;
  const int sh = ((j7 >> 1) | ((j7 & 1) << 2)) << 2;

  int ncol[2], cglob[2], cloc[2];
#pragma unroll
  for (int t2 = 0; t2 < 2; ++t2) {
    ncol[t2]  = n0 + wid * 32 + t2 * 16 + c16;
    cglob[t2] = ncol[t2] >> 3;
    cloc[t2]  = wid * 4 + t2 * 2 + (c16 >> 3);   // local word-col 0..31
  }

  const int kbeg = by * SLICE_K;
  const int g0   = kbeg >> 7;     // first of 2 quant groups in this slice

  // ---- issue ALL global loads up front ----
  const int qr = tid >> 3;        // 0..63
  const int qc = tid & 7;         // 0..7 -> words qc*4..qc*4+3
  int4 qv[4];
#pragma unroll
  for (int rr = 0; rr < 4; ++rr)
    qv[rr] = *reinterpret_cast<const int4*>(
        qw + (long)(kbeg + rr * 64 + qr) * NC + c0 + qc * 4);

  const int xm = tid >> 4;        // 0..31
  const int xo = tid & 15;        // 0..15
  const float* xrow = x + (long)xm * K + kbeg + xo * 16;
  const float4 xa = *reinterpret_cast<const float4*>(xrow);
  const float4 xb = *reinterpret_cast<const float4*>(xrow + 4);
  const float4 xc = *reinterpret_cast<const float4*>(xrow + 8);
  const float4 xd = *reinterpret_cast<const float4*>(xrow + 12);

  // group scalars -> packed f16 constants (while loads are in flight)
  f16x2 s2[2][2], mz2[2][2];      // [group][n-tile]
#pragma unroll
  for (int g = 0; g < 2; ++g)
#pragma unroll
    for (int t2 = 0; t2 < 2; ++t2) {
      const int zq = qz[(g0 + g) * NC + cglob[t2]];
      const _Float16 s16 = (_Float16)sc[(g0 + g) * N + ncol[t2]];
      const _Float16 mz  = (_Float16)(-(float)(1024 + ((zq >> sh) & 15)));
      s2[g][t2][0] = s16; s2[g][t2][1] = s16;
      mz2[g][t2][0] = mz; mz2[g][t2][1] = mz;
    }

  // ---- LDS writes ----
#pragma unroll
  for (int rr = 0; rr < 4; ++rr) {
    const int r = rr * 64 + qr;
    lqs[(qc * 4 + 0) * QS + r] = qv[rr].x;
    lqs[(qc * 4 + 1) * QS + r] = qv[rr].y;
    lqs[(qc * 4 + 2) * QS + r] = qv[rr].z;
    lqs[(qc * 4 + 3) * QS + r] = qv[rr].w;
  }
  {
    union { f16x2 h2[4]; f16x8 h8; } u0, u1;
    u0.h2[0] = __builtin_bit_cast(f16x2, __builtin_amdgcn_cvt_pkrtz(xa.x, xa.y));
    u0.h2[1] = __builtin_bit_cast(f16x2, __builtin_amdgcn_cvt_pkrtz(xa.z, xa.w));
    u0.h2[2] = __builtin_bit_cast(f16x2, __builtin_amdgcn_cvt_pkrtz(xb.x, xb.y));
    u0.h2[3] = __builtin_bit_cast(f16x2, __builtin_amdgcn_cvt_pkrtz(xb.z, xb.w));
    u1.h2[0] = __builtin_bit_cast(f16x2, __builtin_amdgcn_cvt_pkrtz(xc.x, xc.y));
    u1.h2[1] = __builtin_bit_cast(f16x2, __builtin_amdgcn_cvt_pkrtz(xc.z, xc.w));
    u1.h2[2] = __builtin_bit_cast(f16x2, __builtin_amdgcn_cvt_pkrtz(xd.x, xd.y));
    u1.h2[3] = __builtin_bit_cast(f16x2, __builtin_amdgcn_cvt_pkrtz(xd.z, xd.w));
    _Float16* dst = &lxh[xm * XSH + xo * 16];
    *reinterpret_cast<f16x8*>(dst)     = u0.h8;
    *reinterpret_cast<f16x8*>(dst + 8) = u1.h8;
  }

  __syncthreads();               // the ONLY barrier

  f32x4 acc[2][2] = {};          // [m-tile][n-tile]

#pragma unroll
  for (int t = 0; t < NT; ++t) {
    const int g = t >> 2;        // quant group (4 steps/group)
    const f16x8 a0 = *reinterpret_cast<const f16x8*>(&lxh[c16 * XSH + t * BK + kq * 8]);
    const f16x8 a1 = *reinterpret_cast<const f16x8*>(&lxh[(c16 + 16) * XSH + t * BK + kq * 8]);

#pragma unroll
    for (int t2 = 0; t2 < 2; ++t2) {
      const int base = cloc[t2] * QS + t * BK + kq * 8;
      f16x8 b;
#pragma unroll
      for (int half = 0; half < 2; ++half) {
        const int4 q4 = *reinterpret_cast<const int4*>(&lqs[base + 4 * half]);
        const unsigned v0 = __builtin_amdgcn_ubfe((unsigned)q4.x, sh, 4);
        const unsigned v1 = __builtin_amdgcn_ubfe((unsigned)q4.y, sh, 4);
        const unsigned v2 = __builtin_amdgcn_ubfe((unsigned)q4.z, sh, 4);
        const unsigned v3 = __builtin_amdgcn_ubfe((unsigned)q4.w, sh, 4);
        const f16x2 h01 = __builtin_bit_cast(f16x2, (v0 | (v1 << 16)) | 0x64006400u);
        const f16x2 h23 = __builtin_bit_cast(f16x2, (v2 | (v3 << 16)) | 0x64006400u);
        const f16x2 w01 = (h01 + mz2[g][t2]) * s2[g][t2];   // exact (v-z), 1 rnd
        const f16x2 w23 = (h23 + mz2[g][t2]) * s2[g][t2];
        b[4 * half]     = w01[0];
        b[4 * half + 1] = w01[1];
        b[4 * half + 2] = w23[0];
        b[4 * half + 3] = w23[1];
      }
      acc[0][t2] = __builtin_amdgcn_mfma_f32_16x16x32_f16(a0, b, acc[0][t2], 0, 0, 0);
      acc[1][t2] = __builtin_amdgcn_mfma_f32_16x16x32_f16(a1, b, acc[1][t2], 0, 0, 0);
    }
  }

  // ---- epilogue: f16 partials, plain stores ----
  _Float16* pp = partial + (long)by * OUT_ELEMS;
#pragma unroll
  for (int mt = 0; mt < 2; ++mt)
#pragma unroll
    for (int t2 = 0; t2 < 2; ++t2)
#pragma unroll
      for (int i = 0; i < 4; ++i) {
        const int row = mt * 16 + kq * 4 + i;
        pp[row * N + ncol[t2]] = (_Float16)acc[mt][t2][i];
      }
}

extern "C" void kernel_launch(void* const* d_in, const int* in_sizes, int n_in,
                              void* d_out, int out_size, void* d_ws, size_t ws_size,
                              hipStream_t stream) {
  const float* x    = (const float*)d_in[0];
  const int* qw     = (const int*)d_in[1];
  const int* qz     = (const int*)d_in[2];
  const float* sc   = (const float*)d_in[3];   // fp16 values delivered as f32
  const float* bias = (const float*)d_in[4];   // fp16 values delivered as f32
  float* out        = (float*)d_out;

  _Float16* partial = (_Float16*)d_ws;         // 16 x 352256 f16 = 11.3 MB

  awq_gemm_kernel<<<dim3(NWG), 512, 0, stream>>>(qw, qz, sc, x, partial);
  reduce_kernel<<<dim3(OUT_ELEMS / (256 * 8)), 256, 0, stream>>>(partial, bias, out);
}